// Round 1
// baseline (1974.170 us; speedup 1.0000x reference)
//
#include <hip/hip_runtime.h>
#include <hip/hip_bf16.h>

#define T_LEN 2048
#define BATCH 128
#define DX 64
#define DH 128
#define KF 192   // DX + DH
#define XB 16    // x staging block (steps)

typedef unsigned int u32;

__device__ __forceinline__ float bf_lo(u32 u){ return __uint_as_float(u << 16); }
__device__ __forceinline__ float bf_hi(u32 u){ return __uint_as_float(u & 0xffff0000u); }

// One workgroup per (batch, direction) sequence: 256 WGs = 1 per CU.
// Thread i: output j = i&127, k-half p = i>>7 (k in [96p, 96p+96)).
// k<64 -> x part, k>=64 -> h part. h broadcast from LDS; weights in VGPRs.
__global__ __launch_bounds__(256, 1) void rnn_scan(
    const float* __restrict__ x,      // [T][B][DX]
    const float* __restrict__ Wf,     // [DH][KF]
    const float* __restrict__ bfv,    // [DH]
    __hip_bfloat16* __restrict__ cat) // [T][B][2*DH]
{
  const int wg  = blockIdx.x;
  const int b   = wg >> 1;
  const int dir = wg & 1;
  const int tid = threadIdx.x;
  const int j   = tid & (DH - 1);
  const int p   = tid >> 7;          // wave-uniform (waves 0,1 -> p=0; 2,3 -> p=1)

  __shared__ float hs[DH];
  __shared__ float part[DH];
  __shared__ float xb[XB][DX];

  // Per-thread weight slice: Wf[j][96p .. 96p+96)
  float w[96];
  {
    const float* wp = Wf + (size_t)j * KF + p * 96;
    #pragma unroll
    for (int r = 0; r < 24; ++r) {
      float4 v = *(const float4*)(wp + r * 4);
      w[r*4+0] = v.x; w[r*4+1] = v.y; w[r*4+2] = v.z; w[r*4+3] = v.w;
    }
  }
  const float bj = bfv[j];
  if (tid < DH) hs[tid] = 0.0f;

  // x prefetch: 256 threads x float4 = 16 steps x 64 floats
  const int xi = tid >> 4;           // 0..15 (step within block)
  const int xk = (tid & 15) * 4;     // 0..60
  float4 xv;
  {
    int s  = xi;
    int tp = dir ? (T_LEN - 1 - s) : s;
    xv = *(const float4*)(x + ((size_t)tp * BATCH + b) * DX + xk);
  }

  // Output pointer: cat[t][b][dir*DH + j], t = dir ? T-1-s : s
  __hip_bfloat16* outp = cat + ((size_t)(dir ? (T_LEN - 1) : 0) * BATCH + b) * (2 * DH)
                         + dir * DH + j;
  const ptrdiff_t ostep = dir ? -(ptrdiff_t)(BATCH * 2 * DH) : (ptrdiff_t)(BATCH * 2 * DH);

  __syncthreads();                   // hs init visible

  for (int s0 = 0; s0 < T_LEN; s0 += XB) {
    // Stage prefetched x block; issue next block's prefetch (latency hides under compute)
    *(float4*)&xb[xi][xk] = xv;
    if (s0 + XB < T_LEN) {
      int s  = s0 + XB + xi;
      int tp = dir ? (T_LEN - 1 - s) : s;
      xv = *(const float4*)(x + ((size_t)tp * BATCH + b) * DX + xk);
    }
    __syncthreads();

    #pragma unroll 1
    for (int i = 0; i < XB; ++i) {
      // 4 independent accumulator chains (1 wave/SIMD -> must break FMA dep chain)
      float a0 = 0.f, a1 = 0.f, a2 = 0.f, a3 = 0.f;
      if (p == 0) {
        const float* xr = xb[i];
        #pragma unroll
        for (int r = 0; r < 64; r += 4) {
          a0 = fmaf(w[r+0], xr[r+0], a0);
          a1 = fmaf(w[r+1], xr[r+1], a1);
          a2 = fmaf(w[r+2], xr[r+2], a2);
          a3 = fmaf(w[r+3], xr[r+3], a3);
        }
        #pragma unroll
        for (int r = 0; r < 32; r += 4) {
          a0 = fmaf(w[64+r+0], hs[r+0], a0);
          a1 = fmaf(w[64+r+1], hs[r+1], a1);
          a2 = fmaf(w[64+r+2], hs[r+2], a2);
          a3 = fmaf(w[64+r+3], hs[r+3], a3);
        }
      } else {
        #pragma unroll
        for (int r = 0; r < 96; r += 4) {
          a0 = fmaf(w[r+0], hs[32+r+0], a0);
          a1 = fmaf(w[r+1], hs[32+r+1], a1);
          a2 = fmaf(w[r+2], hs[32+r+2], a2);
          a3 = fmaf(w[r+3], hs[32+r+3], a3);
        }
        part[j] = (a0 + a1) + (a2 + a3);
      }
      __syncthreads();               // part visible to p==0
      if (p == 0) {
        float tot = (a0 + a1) + (a2 + a3) + part[j] + bj;
        float e  = __expf(2.0f * tot);
        float hn = 1.0f - 2.0f / (e + 1.0f);   // tanh
        hs[j] = hn;
        *outp = __float2bfloat16(hn);
      }
      __syncthreads();               // h_next visible before next step's reads
      outp += ostep;
    }
  }
}

// Thread-per-(s,b)-row: 64 logits in registers, Wo^T broadcast from LDS,
// log-softmax + targets dot, wave-reduce, atomicAdd into scalar loss.
__global__ __launch_bounds__(256) void proj_loss(
    const __hip_bfloat16* __restrict__ cat, // [T*B][256]
    const float* __restrict__ Wo,           // [64][256]
    const float* __restrict__ bo,           // [64]
    const float* __restrict__ tg,           // [T*B][64]
    float* __restrict__ out)
{
  __shared__ float WoT[256][64];            // exactly 64 KiB
  const int tid = threadIdx.x;
  for (int i = tid; i < 64 * 256; i += 256) {
    int o = i >> 8, k = i & 255;
    WoT[k][o] = Wo[i];                      // one-time transpose (conflicted store, negligible)
  }
  __syncthreads();

  const size_t row = (size_t)blockIdx.x * 256 + tid;
  const __hip_bfloat16* cr = cat + row * 256;
  const float* tr = tg + row * 64;

  float acc[64];
  #pragma unroll
  for (int o = 0; o < 64; ++o) acc[o] = bo[o];

  for (int k8 = 0; k8 < 32; ++k8) {
    uint4 pk = *(const uint4*)(cr + k8 * 8);
    float c[8];
    c[0] = bf_lo(pk.x); c[1] = bf_hi(pk.x);
    c[2] = bf_lo(pk.y); c[3] = bf_hi(pk.y);
    c[4] = bf_lo(pk.z); c[5] = bf_hi(pk.z);
    c[6] = bf_lo(pk.w); c[7] = bf_hi(pk.w);
    const float* wr = &WoT[k8 * 8][0];
    #pragma unroll
    for (int kk = 0; kk < 8; ++kk) {
      #pragma unroll
      for (int o = 0; o < 64; ++o)
        acc[o] = fmaf(c[kk], wr[kk * 64 + o], acc[o]);   // broadcast LDS read
    }
  }

  // log-softmax over 64 logits
  float m = acc[0];
  #pragma unroll
  for (int o = 1; o < 64; ++o) m = fmaxf(m, acc[o]);
  float se = 0.f;
  #pragma unroll
  for (int o = 0; o < 64; ++o) se += __expf(acc[o] - m);
  float lse = m + __logf(se);

  float csum = 0.f;
  #pragma unroll
  for (int o = 0; o < 64; o += 4) {
    float4 t4 = *(const float4*)(tr + o);
    csum = fmaf(t4.x, lse - acc[o+0], csum);
    csum = fmaf(t4.y, lse - acc[o+1], csum);
    csum = fmaf(t4.z, lse - acc[o+2], csum);
    csum = fmaf(t4.w, lse - acc[o+3], csum);
  }
  // csum = sum_o t*(lse - logit) = -sum_o t*logp  (positive)
  #pragma unroll
  for (int off = 32; off; off >>= 1) csum += __shfl_down(csum, off);
  if ((tid & 63) == 0) atomicAdd(out, csum * (1.0f / BATCH));
}

extern "C" void kernel_launch(void* const* d_in, const int* in_sizes, int n_in,
                              void* d_out, int out_size, void* d_ws, size_t ws_size,
                              hipStream_t stream)
{
  const float* inps = (const float*)d_in[0];
  const float* tg   = (const float*)d_in[1];
  const float* Wf   = (const float*)d_in[2];
  const float* bfv  = (const float*)d_in[3];
  const float* Wo   = (const float*)d_in[4];
  const float* bo   = (const float*)d_in[5];
  float* out = (float*)d_out;

  // workspace: cat = [T][B][2*DH] bf16 = 134,217,728 B
  __hip_bfloat16* cat = (__hip_bfloat16*)d_ws;

  hipMemsetAsync(out, 0, sizeof(float), stream);
  rnn_scan<<<BATCH * 2, 256, 0, stream>>>(inps, Wf, bfv, cat);
  proj_loss<<<(T_LEN * BATCH) / 256, 256, 0, stream>>>(cat, Wo, bo, tg, out);
}